// Round 6
// baseline (110.370 us; speedup 1.0000x reference)
//
#include <hip/hip_runtime.h>

typedef unsigned short u16;
typedef __attribute__((ext_vector_type(8))) short short8;
typedef __attribute__((ext_vector_type(4))) float f32x4;

#define INVT 14.285714285714286f   // 1/0.07
#define KEXP 20.617062471830945f   // INVT*log2(e): exp((x-1)/T) = exp2(x*KEXP - KEXP)

__device__ __forceinline__ u16 f2bf(float f) {
  union { float f; unsigned u; } v; v.f = f;
  unsigned u = v.u;
  u += 0x7fffu + ((u >> 16) & 1u);  // round-to-nearest-even
  return (u16)(u >> 16);
}

// Kernel 1: one 128x128 triangular tile (bi<=bj) of S = F̂ F̂ᵀ per block,
// with normalization fused: each block loads its two 128-row fp32 slabs,
// normalizes in-register (identical code path for both sides -> bit-identical
// bf16 everywhere), writes XOR-swizzled bf16 granules to LDS, MFMAs, then
// exp((s-1)/T) -> column sums (+ row sums off-diag) -> pure stores into P.
// Diagonal tiles also emit dvec (from S[i,i]); tiles with bj-bi==NB/2 emit pos.
__global__ __launch_bounds__(256, 2) void gemm_exp_kernel(
    const float* __restrict__ f1, const float* __restrict__ f2,
    float* __restrict__ P, float* __restrict__ dvec, float* __restrict__ pos,
    float* __restrict__ accum, int* __restrict__ done, int N, int TWO_N) {
  __shared__ __align__(16) u16 At[128 * 128];  // 32 KB
  __shared__ __align__(16) u16 Bt[128 * 128];  // 32 KB
  __shared__ float colsum[128];
  __shared__ float rowsum[128];
  const int tid = threadIdx.x;
  const int wave = tid >> 6, lane = tid & 63;
  // triangular decode: p -> (bj, bi<=bj)
  int p = blockIdx.x;
  if (p == 0 && tid == 0) { *accum = 0.0f; *done = 0; }  // init for reduce pass
  int bj = (int)((sqrtf(8.0f * (float)p + 1.0f) - 1.0f) * 0.5f);
  while ((bj + 1) * (bj + 2) / 2 <= p) ++bj;
  while (bj * (bj + 1) / 2 > p) --bj;
  const int bi = p - bj * (bj + 1) / 2;
  const bool diag = (bi == bj);

  if (tid < 128) { colsum[tid] = 0.0f; rowsum[tid] = 0.0f; }

  // ---- fused normalize + stage (both sides through ONE code path) ----
  const int r = tid >> 1, h = tid & 1;  // 2 threads/row, 64 f32 each
#pragma unroll
  for (int s = 0; s < 2; ++s) {
    if (s == 0 && diag) continue;  // diag: only stage Bt
    const int rb = s ? bj : bi;
    const int g = rb * 128 + r;
    const float* src = (g < N) ? (f1 + (size_t)g * 128) : (f2 + (size_t)(g - N) * 128);
    const float4* s4 = (const float4*)src + h * 16;
    float4 v[16];
    float ss = 0.0f;
#pragma unroll
    for (int k = 0; k < 16; ++k) {
      v[k] = s4[k];
      ss += v[k].x * v[k].x + v[k].y * v[k].y + v[k].z * v[k].z + v[k].w * v[k].w;
    }
    ss += __shfl_xor(ss, 1);  // partner thread (other half of the row)
    const float inv = 1.0f / fmaxf(sqrtf(ss), 1e-12f);
    u16* dst = s ? Bt : At;
#pragma unroll
    for (int k = 0; k < 8; ++k) {
      float4 a = v[2 * k], b = v[2 * k + 1];
      short8 gr;
      gr[0] = (short)f2bf(a.x * inv); gr[1] = (short)f2bf(a.y * inv);
      gr[2] = (short)f2bf(a.z * inv); gr[3] = (short)f2bf(a.w * inv);
      gr[4] = (short)f2bf(b.x * inv); gr[5] = (short)f2bf(b.y * inv);
      gr[6] = (short)f2bf(b.z * inv); gr[7] = (short)f2bf(b.w * inv);
      const int gc = (h * 8 + k) ^ (r & 7);  // XOR-swizzled granule column
      *(short8*)&dst[(r * 16 + gc) * 8] = gr;
    }
  }
  __syncthreads();

  // ---- MFMA: 2x2 waves, each 64x64, 16x16x32 bf16 ----
  const int wr = wave >> 1, wc = wave & 1;
  const int q = lane >> 4, m = lane & 15;
  const u16* asrc = diag ? Bt : At;
  f32x4 acc[4][4];
#pragma unroll
  for (int fr = 0; fr < 4; ++fr)
#pragma unroll
    for (int cf = 0; cf < 4; ++cf) acc[fr][cf] = (f32x4)(0.0f);

#pragma unroll
  for (int ks = 0; ks < 4; ++ks) {
    const int c = ks * 4 + q;  // k-granule (8 bf16 each)
    short8 av[4], bv[4];
#pragma unroll
    for (int fr = 0; fr < 4; ++fr) {
      int rr = wr * 64 + fr * 16 + m;
      av[fr] = *(const short8*)&asrc[rr * 128 + ((c ^ (rr & 7)) * 8)];
    }
#pragma unroll
    for (int cf = 0; cf < 4; ++cf) {
      int rr = wc * 64 + cf * 16 + m;
      bv[cf] = *(const short8*)&Bt[rr * 128 + ((c ^ (rr & 7)) * 8)];
    }
#pragma unroll
    for (int fr = 0; fr < 4; ++fr)
#pragma unroll
      for (int cf = 0; cf < 4; ++cf)
        acc[fr][cf] = __builtin_amdgcn_mfma_f32_16x16x32_bf16(av[fr], bv[cf], acc[fr][cf], 0, 0, 0);
  }

  // ---- dvec / pos extraction from raw scores ----
  // C-layout: local row = q*4+rg (+fr*16+wr*64), local col = m (+cf*16+wc*64).
  // Diagonal lanes: q == m>>2 (then rg = m&3), waves with wr==wc, frags fr==cf.
  const bool dlane = (q == (m >> 2)) && (wr == wc);
  if (diag && dlane) {
#pragma unroll
    for (int fr = 0; fr < 4; ++fr) {
      float sv = acc[fr][fr][m & 3];
      dvec[bj * 128 + wr * 64 + fr * 16 + m] = exp2f(fmaf(sv, KEXP, -KEXP));
    }
  }
  if ((bj - bi) * 256 == TWO_N && dlane) {  // bj == bi + NB/2: pos pairs
#pragma unroll
    for (int fr = 0; fr < 4; ++fr) {
      float sv = acc[fr][fr][m & 3];
      int a = bi * 128 + wr * 64 + fr * 16 + m;
      pos[a] = sv;
      pos[a + N] = sv;
    }
  }

  // ---- exp + column sums (and off-diag row sums) ----
  float cs[4] = {0.f, 0.f, 0.f, 0.f};
  float v[16];
#pragma unroll
  for (int i = 0; i < 16; ++i) v[i] = 0.f;
#pragma unroll
  for (int cf = 0; cf < 4; ++cf)
#pragma unroll
    for (int fr = 0; fr < 4; ++fr)
#pragma unroll
      for (int rg = 0; rg < 4; ++rg) {
        float e = exp2f(fmaf(acc[fr][cf][rg], KEXP, -KEXP));
        cs[cf] += e;
        v[fr * 4 + rg] += e;
      }
#pragma unroll
  for (int cf = 0; cf < 4; ++cf) {
    cs[cf] += __shfl_xor(cs[cf], 16);
    cs[cf] += __shfl_xor(cs[cf], 32);
    if (q == 0) atomicAdd(&colsum[wc * 64 + cf * 16 + m], cs[cf]);
  }
  // row sums (off-diag only): value-halving butterfly over the 16 m-lanes;
  // after steps 8/4/2/1 lane (q,m) holds the sum for idx==m -> row
  // (m>>2)*16 + q*4 + (m&3). One conflict-free LDS atomic per lane.
  if (!diag) {
    float t16[16];
#pragma unroll
    for (int i = 0; i < 16; ++i) t16[i] = __shfl_xor(v[i], 8);
    bool hi = (m & 8) != 0;
#pragma unroll
    for (int i = 0; i < 8; ++i) v[i] = hi ? (v[i + 8] + t16[i + 8]) : (v[i] + t16[i]);
#pragma unroll
    for (int i = 0; i < 8; ++i) t16[i] = __shfl_xor(v[i], 4);
    hi = (m & 4) != 0;
#pragma unroll
    for (int i = 0; i < 4; ++i) v[i] = hi ? (v[i + 4] + t16[i + 4]) : (v[i] + t16[i]);
#pragma unroll
    for (int i = 0; i < 4; ++i) t16[i] = __shfl_xor(v[i], 2);
    hi = (m & 2) != 0;
#pragma unroll
    for (int i = 0; i < 2; ++i) v[i] = hi ? (v[i + 2] + t16[i + 2]) : (v[i] + t16[i]);
    t16[0] = __shfl_xor(v[0], 1);
    t16[1] = __shfl_xor(v[1], 1);
    v[0] = (m & 1) ? (v[1] + t16[1]) : (v[0] + t16[0]);
    atomicAdd(&rowsum[wr * 64 + (m >> 2) * 16 + q * 4 + (m & 3)], v[0]);
  }
  __syncthreads();
  if (tid < 128) {
    P[(size_t)bi * TWO_N + bj * 128 + tid] = colsum[tid];
    if (!diag) P[(size_t)bj * TWO_N + bi * 128 + tid] = rowsum[tid];
  }
}

// Kernel 2: E_j = sum_o P[o][j] (coalesced, L2-hot); term_j; block partial ->
// one accum atomic per block; ticket-last block writes out (single RMW).
__global__ __launch_bounds__(256) void reduce_kernel(
    const float* __restrict__ P, const float* __restrict__ dvec,
    const float* __restrict__ pos, float* __restrict__ accum,
    int* __restrict__ done, float* __restrict__ out, int TWO_N, int NB) {
  __shared__ float wpart[4];
  __shared__ int ticket_s;
  const int tid = threadIdx.x;
  const int wave = tid >> 6, lane = tid & 63;
  const int j = blockIdx.x * 256 + tid;
  float e = 0.0f;
#pragma unroll 8
  for (int o = 0; o < NB; ++o) e += P[(size_t)o * TWO_N + j];
  float term = (pos[j] - 1.0f) * INVT - logf(e - dvec[j]);
#pragma unroll
  for (int o = 32; o; o >>= 1) term += __shfl_xor(term, o);
  if (lane == 0) wpart[wave] = term;
  __syncthreads();
  if (tid == 0) {
    atomicAdd(accum, wpart[0] + wpart[1] + wpart[2] + wpart[3]);
    __threadfence();
    ticket_s = atomicAdd(done, 1);
    if (ticket_s == gridDim.x - 1) {
      float tot = atomicAdd(accum, 0.0f);  // device-scope RMW: sees all adds
      out[0] = tot * (-1.0f / (float)TWO_N);
    }
  }
}

extern "C" void kernel_launch(void* const* d_in, const int* in_sizes, int n_in,
                              void* d_out, int out_size, void* d_ws, size_t ws_size,
                              hipStream_t stream) {
  const float* f1 = (const float*)d_in[0];
  const float* f2 = (const float*)d_in[1];
  int N = in_sizes[0] / 128;        // 4096
  int TWO_N = 2 * N;                // 8192
  int NB = TWO_N / 128;             // 64
  int NT = NB * (NB + 1) / 2;       // 2080

  char* ws = (char*)d_ws;
  float* P     = (float*)ws;                                // NB*2N f32 = 2 MB
  float* dvec  = P + (size_t)NB * TWO_N;                    // 2N f32
  float* pos   = dvec + TWO_N;                              // 2N f32
  float* accum = pos + TWO_N;                               // 1 f32
  int*   done  = (int*)(accum + 1);                         // 1 int

  gemm_exp_kernel<<<NT, 256, 0, stream>>>(f1, f2, P, dvec, pos, accum, done,
                                          N, TWO_N);
  reduce_kernel<<<TWO_N / 256, 256, 0, stream>>>(P, dvec, pos, accum, done,
                                                 (float*)d_out, TWO_N, NB);
}

// Round 7
// 106.808 us; speedup vs baseline: 1.0333x; 1.0333x over previous
//
#include <hip/hip_runtime.h>

typedef unsigned short u16;
typedef __attribute__((ext_vector_type(8))) short short8;
typedef __attribute__((ext_vector_type(4))) float f32x4;

#define INVT 14.285714285714286f   // 1/0.07
#define KEXP 20.617062471830945f   // INVT*log2(e): exp((x-1)/T) = exp2(x*KEXP - KEXP)

__device__ __forceinline__ u16 f2bf(float f) {
  union { float f; unsigned u; } v; v.f = f;
  unsigned u = v.u;
  u += 0x7fffu + ((u >> 16) & 1u);  // round-to-nearest-even
  return (u16)(u >> 16);
}

// Kernel 1: lean normalize+cast only (dvec/pos come from the MFMA tiles).
// 8 threads/row, 16 f32 each; 256 blocks x 256 threads.
__global__ __launch_bounds__(256) void norm_kernel(
    const float* __restrict__ f1, const float* __restrict__ f2,
    u16* __restrict__ F, float* __restrict__ accum, int* __restrict__ done,
    int N) {
  const int t = blockIdx.x * 256 + threadIdx.x;
  if (t == 0) { *accum = 0.0f; *done = 0; }
  const int row = t >> 3, h = t & 7;
  if (row >= 2 * N) return;
  const float* src = (row < N) ? (f1 + (size_t)row * 128)
                               : (f2 + (size_t)(row - N) * 128);
  const float4* s4 = (const float4*)src + h * 4;
  float4 v[4];
  float ss = 0.0f;
#pragma unroll
  for (int k = 0; k < 4; ++k) {
    v[k] = s4[k];
    ss += v[k].x * v[k].x + v[k].y * v[k].y + v[k].z * v[k].z + v[k].w * v[k].w;
  }
  ss += __shfl_xor(ss, 1);
  ss += __shfl_xor(ss, 2);
  ss += __shfl_xor(ss, 4);  // full row sum across the 8 row-threads
  const float inv = 1.0f / fmaxf(sqrtf(ss), 1e-12f);
  u16* dst = F + (size_t)row * 128 + h * 16;
#pragma unroll
  for (int k = 0; k < 2; ++k) {
    float4 a = v[2 * k], b = v[2 * k + 1];
    short8 gr;
    gr[0] = (short)f2bf(a.x * inv); gr[1] = (short)f2bf(a.y * inv);
    gr[2] = (short)f2bf(a.z * inv); gr[3] = (short)f2bf(a.w * inv);
    gr[4] = (short)f2bf(b.x * inv); gr[5] = (short)f2bf(b.y * inv);
    gr[6] = (short)f2bf(b.z * inv); gr[7] = (short)f2bf(b.w * inv);
    *(short8*)(dst + k * 8) = gr;
  }
}

// Kernel 2: one 128x128 triangular tile (bi<=bj) per 4-wave block.
// NO LDS, NO barriers: each wave loads its MFMA fragments register-direct
// from F (L2-resident), computes exp((s-1)/T), and stores PER-WAVE partials:
//   col-sum partial  -> Pc[bi*2+wr][bj*128 + wc*64 + c]   (wave's 64 rows)
//   row-sum partial  -> Qr[bj*2+wc][bi*128 + wr*64 + r]   (wave's 64 cols, off-diag)
// Each cell written exactly once; no atomics, no cross-wave traffic.
// Diag tiles emit dvec from S[i,i]; tiles with bj-bi==NB/2 emit pos.
__global__ __launch_bounds__(256, 3) void gemm_exp_kernel(
    const u16* __restrict__ F, float* __restrict__ Pc, float* __restrict__ Qr,
    float* __restrict__ dvec, float* __restrict__ pos, int N, int TWO_N) {
  const int tid = threadIdx.x;
  const int wave = tid >> 6, lane = tid & 63;
  // triangular decode: p -> (bj, bi<=bj)
  int p = blockIdx.x;
  int bj = (int)((sqrtf(8.0f * (float)p + 1.0f) - 1.0f) * 0.5f);
  while ((bj + 1) * (bj + 2) / 2 <= p) ++bj;
  while (bj * (bj + 1) / 2 > p) --bj;
  const int bi = p - bj * (bj + 1) / 2;
  const bool diag = (bi == bj);

  const int wr = wave >> 1, wc = wave & 1;  // 2x2 waves, each 64x64
  const int q = lane >> 4, m = lane & 15;

  // Fragment base rows: lane m covers row (fr*16 + m); quad q covers k-granule.
  const u16* Arow = F + ((size_t)(bi * 128 + wr * 64 + m)) * 128;
  const u16* Brow = F + ((size_t)(bj * 128 + wc * 64 + m)) * 128;

  f32x4 acc[4][4];
#pragma unroll
  for (int fr = 0; fr < 4; ++fr)
#pragma unroll
    for (int cf = 0; cf < 4; ++cf) acc[fr][cf] = (f32x4)(0.0f);

#pragma unroll
  for (int ks = 0; ks < 4; ++ks) {
    const int ko = (ks * 4 + q) * 8;  // element offset of this quad's k-granule
    short8 av[4], bv[4];
#pragma unroll
    for (int fr = 0; fr < 4; ++fr) av[fr] = *(const short8*)(Arow + fr * 2048 + ko);
#pragma unroll
    for (int cf = 0; cf < 4; ++cf) bv[cf] = *(const short8*)(Brow + cf * 2048 + ko);
#pragma unroll
    for (int fr = 0; fr < 4; ++fr)
#pragma unroll
      for (int cf = 0; cf < 4; ++cf)
        acc[fr][cf] = __builtin_amdgcn_mfma_f32_16x16x32_bf16(av[fr], bv[cf], acc[fr][cf], 0, 0, 0);
  }

  // ---- dvec / pos extraction from raw scores (verified R6) ----
  // C-layout: local row = q*4+rg (+fr*16+wr*64), local col = m (+cf*16+wc*64).
  const bool dlane = (q == (m >> 2)) && (wr == wc);
  if (diag && dlane) {
#pragma unroll
    for (int fr = 0; fr < 4; ++fr) {
      float sv = acc[fr][fr][m & 3];
      dvec[bj * 128 + wr * 64 + fr * 16 + m] = exp2f(fmaf(sv, KEXP, -KEXP));
    }
  }
  if ((bj - bi) * 256 == TWO_N && dlane) {  // bj == bi + NB/2: pos pairs
#pragma unroll
    for (int fr = 0; fr < 4; ++fr) {
      float sv = acc[fr][fr][m & 3];
      int a = bi * 128 + wr * 64 + fr * 16 + m;
      pos[a] = sv;
      pos[a + N] = sv;
    }
  }

  // ---- exp + per-wave column sums and (off-diag) row sums ----
  float cs[4] = {0.f, 0.f, 0.f, 0.f};
  float v[16];
#pragma unroll
  for (int i = 0; i < 16; ++i) v[i] = 0.f;
#pragma unroll
  for (int cf = 0; cf < 4; ++cf)
#pragma unroll
    for (int fr = 0; fr < 4; ++fr)
#pragma unroll
      for (int rg = 0; rg < 4; ++rg) {
        float e = exp2f(fmaf(acc[fr][cf][rg], KEXP, -KEXP));
        cs[cf] += e;
        v[fr * 4 + rg] += e;
      }
  // column sums: reduce across the 4 quads (rows) -> all lanes hold totals
#pragma unroll
  for (int cf = 0; cf < 4; ++cf) {
    cs[cf] += __shfl_xor(cs[cf], 16);
    cs[cf] += __shfl_xor(cs[cf], 32);
  }
  if (q == 0) {
    float* dst = Pc + (size_t)(bi * 2 + wr) * TWO_N + bj * 128 + wc * 64 + m;
    dst[0] = cs[0]; dst[16] = cs[1]; dst[32] = cs[2]; dst[48] = cs[3];
  }
  // row sums (off-diag only): value-halving butterfly over the 16 m-lanes;
  // after steps 8/4/2/1 lane (q,m) holds the sum for idx==m -> local row
  // (m>>2)*16 + q*4 + (m&3). One dword store per lane. (verified R5/R6)
  if (!diag) {
    float t16[16];
#pragma unroll
    for (int i = 0; i < 16; ++i) t16[i] = __shfl_xor(v[i], 8);
    bool hi = (m & 8) != 0;
#pragma unroll
    for (int i = 0; i < 8; ++i) v[i] = hi ? (v[i + 8] + t16[i + 8]) : (v[i] + t16[i]);
#pragma unroll
    for (int i = 0; i < 8; ++i) t16[i] = __shfl_xor(v[i], 4);
    hi = (m & 4) != 0;
#pragma unroll
    for (int i = 0; i < 4; ++i) v[i] = hi ? (v[i + 4] + t16[i + 4]) : (v[i] + t16[i]);
#pragma unroll
    for (int i = 0; i < 4; ++i) t16[i] = __shfl_xor(v[i], 2);
    hi = (m & 2) != 0;
#pragma unroll
    for (int i = 0; i < 2; ++i) v[i] = hi ? (v[i + 2] + t16[i + 2]) : (v[i] + t16[i]);
    t16[0] = __shfl_xor(v[0], 1);
    t16[1] = __shfl_xor(v[1], 1);
    v[0] = (m & 1) ? (v[1] + t16[1]) : (v[0] + t16[0]);
    Qr[(size_t)(bj * 2 + wc) * TWO_N + bi * 128 + wr * 64 +
       ((m >> 2) * 16 + q * 4 + (m & 3))] = v[0];
  }
}

// Kernel 3: E_j = sum of 128 per-wave partials (split between Pc and Qr by
// the triangular ranges); term_j; block partial -> one accum atomic;
// ticket-last block writes out.
__global__ __launch_bounds__(256) void reduce_kernel(
    const float* __restrict__ Pc, const float* __restrict__ Qr,
    const float* __restrict__ dvec, const float* __restrict__ pos,
    float* __restrict__ accum, int* __restrict__ done, float* __restrict__ out,
    int TWO_N) {
  __shared__ float wpart[4];
  __shared__ int ticket_s;
  const int tid = threadIdx.x;
  const int wave = tid >> 6, lane = tid & 63;
  const int j = blockIdx.x * 256 + tid;
  const int split = 2 * (j >> 7) + 2;  // wave-uniform (128-sized col-blocks)
  float e = 0.0f;
  const float* pc = Pc + j;
  const float* qr = Qr + j;
#pragma unroll 4
  for (int a = 0; a < split; ++a) e += pc[(size_t)a * TWO_N];
#pragma unroll 4
  for (int c = split; c < 128; ++c) e += qr[(size_t)c * TWO_N];
  float term = (pos[j] - 1.0f) * INVT - logf(e - dvec[j]);
#pragma unroll
  for (int o = 32; o; o >>= 1) term += __shfl_xor(term, o);
  if (lane == 0) wpart[wave] = term;
  __syncthreads();
  if (tid == 0) {
    atomicAdd(accum, wpart[0] + wpart[1] + wpart[2] + wpart[3]);
    __threadfence();
    ticket_s = atomicAdd(done, 1);
    if (ticket_s == gridDim.x - 1) {
      float tot = atomicAdd(accum, 0.0f);  // device-scope RMW: sees all adds
      out[0] = tot * (-1.0f / (float)TWO_N);
    }
  }
}

extern "C" void kernel_launch(void* const* d_in, const int* in_sizes, int n_in,
                              void* d_out, int out_size, void* d_ws, size_t ws_size,
                              hipStream_t stream) {
  const float* f1 = (const float*)d_in[0];
  const float* f2 = (const float*)d_in[1];
  int N = in_sizes[0] / 128;        // 4096
  int TWO_N = 2 * N;                // 8192
  int NB = TWO_N / 128;             // 64
  int NT = NB * (NB + 1) / 2;       // 2080

  char* ws = (char*)d_ws;
  u16*   F     = (u16*)ws;                                  // 2 MB
  float* Pc    = (float*)(ws + (size_t)TWO_N * 128 * 2);    // 128*2N f32 = 4 MB
  float* Qr    = Pc + (size_t)2 * NB * TWO_N;               // 128*2N f32 = 4 MB
  float* dvec  = Qr + (size_t)2 * NB * TWO_N;               // 2N f32
  float* pos   = dvec + TWO_N;                              // 2N f32
  float* accum = pos + TWO_N;                               // 1 f32
  int*   done  = (int*)(accum + 1);                         // 1 int

  norm_kernel<<<(TWO_N * 8) / 256, 256, 0, stream>>>(f1, f2, F, accum, done, N);
  gemm_exp_kernel<<<NT, 256, 0, stream>>>(F, Pc, Qr, dvec, pos, N, TWO_N);
  reduce_kernel<<<TWO_N / 256, 256, 0, stream>>>(Pc, Qr, dvec, pos, accum, done,
                                                 (float*)d_out, TWO_N);
}